// Round 1
// baseline (246.942 us; speedup 1.0000x reference)
//
#include <hip/hip_runtime.h>

#define B_DIM 4
#define L_TOK 4096
#define D_DIM 2048
#define R_STEPS 10
#define G_TOK 410               // ceil(4096/10)
#define NROWS (B_DIM * G_TOK)   // 1640

// ws layout: [0,64) flags (uint32 x16), [64, 64+NROWS*256) mask bytes (1 bit/elem, 256 B/row)

__device__ __forceinline__ float waveMaxF(float v) {
#pragma unroll
  for (int o = 32; o > 0; o >>= 1) v = fmaxf(v, __shfl_down(v, o, 64));
  return v;
}

__global__ __launch_bounds__(256) void qact_flag0(const float* __restrict__ x,
                                                  const float* __restrict__ s,
                                                  unsigned int* __restrict__ flags) {
  __shared__ float red[4];
  int row = blockIdx.x;
  int b = row / G_TOK, g = row % G_TOK;
  int tok = g * R_STEPS;  // r = 0, always < L_TOK (max 4090)
  const float* xp = x + ((size_t)(b * L_TOK + tok)) * D_DIM + threadIdx.x * 8;
  float4 v0 = *(const float4*)xp;
  float4 v1 = *(const float4*)(xp + 4);
  float m = fmaxf(fmaxf(fmaxf(fabsf(v0.x), fabsf(v0.y)), fmaxf(fabsf(v0.z), fabsf(v0.w))),
                  fmaxf(fmaxf(fabsf(v1.x), fabsf(v1.y)), fmaxf(fabsf(v1.z), fabsf(v1.w))));
  m = waveMaxF(m);
  int lane = threadIdx.x & 63, wid = threadIdx.x >> 6;
  if (lane == 0) red[wid] = m;
  __syncthreads();
  if (threadIdx.x == 0) {
    float M = fmaxf(fmaxf(red[0], red[1]), fmaxf(red[2], red[3]));
    float dyn = M / 7.0f;
    if (dyn > s[tok]) atomicOr(&flags[0], 1u);
  }
}

__global__ __launch_bounds__(256) void qact_step(const float* __restrict__ x,
                                                 const float* __restrict__ s,
                                                 float* __restrict__ y,
                                                 unsigned char* __restrict__ mask,
                                                 unsigned int* __restrict__ flags,
                                                 int r) {
  __shared__ double redS1[4], redS2[4];
  __shared__ float redM[4], redN[4];

  int row = blockIdx.x;
  int b = row / G_TOK, g = row % G_TOK;
  int tok = g * R_STEPS + r;
  if (tok >= L_TOK) return;  // fully-padded row: contributes nothing (uniform per block)

  int tid = threadIdx.x;
  int lane = tid & 63, wid = tid >> 6;
  const size_t xoff = ((size_t)(b * L_TOK + tok)) * D_DIM + (size_t)tid * 8;

  float xv[8];
  {
    float4 v0 = *(const float4*)(x + xoff);
    float4 v1 = *(const float4*)(x + xoff + 4);
    xv[0] = v0.x; xv[1] = v0.y; xv[2] = v0.z; xv[3] = v0.w;
    xv[4] = v1.x; xv[5] = v1.y; xv[6] = v1.z; xv[7] = v1.w;
  }

  unsigned int mb = mask[(size_t)row * 256 + tid];
  bool flag = flags[r] != 0u;  // uniform across grid

  // a = |inlier| with the carried (old) mask; masked elements are exactly 0
  float a[8];
#pragma unroll
  for (int i = 0; i < 8; ++i) a[i] = ((mb >> i) & 1u) ? 0.0f : fabsf(xv[i]);

  if (flag) {
    double s1 = 0.0, s2 = 0.0;
#pragma unroll
    for (int i = 0; i < 8; ++i) {
      double ad = (double)a[i];
      s1 += ad;
      s2 += ad * ad;
    }
#pragma unroll
    for (int o = 32; o > 0; o >>= 1) {
      s1 += __shfl_down(s1, o, 64);
      s2 += __shfl_down(s2, o, 64);
    }
    if (lane == 0) { redS1[wid] = s1; redS2[wid] = s2; }
    __syncthreads();
    double S1 = redS1[0] + redS1[1] + redS1[2] + redS1[3];
    double S2 = redS2[0] + redS2[1] + redS2[2] + redS2[3];
    double mean = S1 / (double)D_DIM;
    double var = (S2 - (double)D_DIM * mean * mean) / (double)(D_DIM - 1);
    var = var > 0.0 ? var : 0.0;
    double thr = mean + 3.0 * sqrt(var);
#pragma unroll
    for (int i = 0; i < 8; ++i)
      if ((double)a[i] > thr) mb |= (1u << i);
    mask[(size_t)row * 256 + tid] = (unsigned char)mb;
  }

  // ---- outputs for this token ----
  float sr = s[tok];
  float outr[8];
  float mo = 0.0f;
#pragma unroll
  for (int i = 0; i < 8; ++i) {
    bool m = (mb >> i) & 1u;
    outr[i] = m ? xv[i] : 0.0f;
    mo = fmaxf(mo, fabsf(outr[i]));
  }
  mo = waveMaxF(mo);
  if (lane == 0) redM[wid] = mo;
  __syncthreads();
  float MO = fmaxf(fmaxf(redM[0], redM[1]), fmaxf(redM[2], redM[3]));
  float out_s = fmaxf(MO, 1e-8f) / 127.0f;

  float out[8];
#pragma unroll
  for (int i = 0; i < 8; ++i) {
    bool m = (mb >> i) & 1u;
    float inl = m ? 0.0f : xv[i];
    float qi = rintf(inl / sr);
    qi = fminf(fmaxf(qi, -7.0f), 7.0f);
    float in_x = qi * sr;
    float qo = rintf(outr[i] / out_s);
    qo = fminf(fmaxf(qo, -127.0f), 127.0f);
    out[i] = in_x + qo * out_s;
  }
  {
    float4 w0 = make_float4(out[0], out[1], out[2], out[3]);
    float4 w1 = make_float4(out[4], out[5], out[6], out[7]);
    *(float4*)(y + xoff) = w0;
    *(float4*)(y + xoff + 4) = w1;
  }

  // ---- contribution to next step's global flag (uses the UPDATED mask) ----
  if (r < R_STEPS - 1) {
    int tok2 = tok + 1;
    float mn = 0.0f;
    if (tok2 < L_TOK) {
      const float* xp2 = x + xoff + D_DIM;
      float4 n0 = *(const float4*)xp2;
      float4 n1 = *(const float4*)(xp2 + 4);
      float nv[8] = {n0.x, n0.y, n0.z, n0.w, n1.x, n1.y, n1.z, n1.w};
#pragma unroll
      for (int i = 0; i < 8; ++i)
        if (!((mb >> i) & 1u)) mn = fmaxf(mn, fabsf(nv[i]));
    }
    mn = waveMaxF(mn);
    if (lane == 0) redN[wid] = mn;
    __syncthreads();
    if (tid == 0) {
      float MN = fmaxf(fmaxf(redN[0], redN[1]), fmaxf(redN[2], redN[3]));
      float dyn = MN / 7.0f;
      float sn = (tok2 < L_TOK) ? s[tok2] : 1.0f;
      if (dyn > sn) atomicOr(&flags[r + 1], 1u);
    }
  }
}

extern "C" void kernel_launch(void* const* d_in, const int* in_sizes, int n_in,
                              void* d_out, int out_size, void* d_ws, size_t ws_size,
                              hipStream_t stream) {
  const float* x = (const float*)d_in[0];
  const float* s = (const float*)d_in[1];
  float* y = (float*)d_out;
  unsigned int* flags = (unsigned int*)d_ws;
  unsigned char* mask = (unsigned char*)d_ws + 64;

  size_t clear_bytes = 64 + (size_t)NROWS * 256;
  hipMemsetAsync(d_ws, 0, clear_bytes, stream);

  qact_flag0<<<NROWS, 256, 0, stream>>>(x, s, flags);
  for (int r = 0; r < R_STEPS; ++r)
    qact_step<<<NROWS, 256, 0, stream>>>(x, s, y, mask, flags, r);
}

// Round 3
// 92.560 us; speedup vs baseline: 2.6679x; 2.6679x over previous
//
#include <hip/hip_runtime.h>

#define L_TOK 4096
#define D_DIM 2048
#define R_STEPS 10
#define G_TOK 410
#define NROWS 1640
#define FB_NBLK 256

typedef unsigned int uint;
typedef unsigned long long u64;

// ws layout (bytes), zeroed each call:
// [0,1280)     flagset[r*32]  (speculative kernel's computed flags, stride 128B)
// [2048,3328)  flags2[r*32]   (fallback's exact flags)
// [3968,3976)  barrier {count, generation}

__device__ __forceinline__ void load8(float* v, const float* p) {
  float4 a = *(const float4*)p;
  float4 b = *(const float4*)(p + 4);
  v[0] = a.x; v[1] = a.y; v[2] = a.z; v[3] = a.w;
  v[4] = b.x; v[5] = b.y; v[6] = b.z; v[7] = b.w;
}
__device__ __forceinline__ void zero8(float* v) {
#pragma unroll
  for (int i = 0; i < 8; ++i) v[i] = 0.0f;
}
__device__ __forceinline__ void store8(float* p, const float* v) {
  *(float4*)p = make_float4(v[0], v[1], v[2], v[3]);
  *(float4*)(p + 4) = make_float4(v[4], v[5], v[6], v[7]);
}

// ---------------- speculative kernel: assume every step's flag == 1 ----------------
__global__ __launch_bounds__(256, 4) void qact_spec(
    const float* __restrict__ x, const float* __restrict__ s,
    float* __restrict__ y, uint* __restrict__ flagset) {
  __shared__ float redM[4];
  __shared__ double redS[4][2];
  __shared__ float redO[4];

  const int tid = threadIdx.x, lane = tid & 63, wid = tid >> 6;
  const int row = blockIdx.x;
  const int b = row / G_TOK, g = row % G_TOK;
  const size_t base = ((size_t)b * L_TOK + (size_t)g * R_STEPS) * D_DIM + (size_t)tid * 8;

  uint m = 0;  // this thread's 8 outlier-mask bits (carried across steps)
  float cur[8], nxt[8];
  load8(cur, x + base);  // token g*10 always < 4096

  for (int r = 0; r < R_STEPS; ++r) {
    const int tok = g * R_STEPS + r;
    const bool valid = tok < L_TOK;  // block-uniform

    // prefetch next token slab (independent of mask state) — hides HBM latency
    if (r + 1 < R_STEPS) {
      if (tok + 1 < L_TOK) load8(nxt, x + base + (size_t)(r + 1) * D_DIM);
      else zero8(nxt);
    }

    // ---- round 1: masked |x|: max (for flag) + fp64 sums (for mean/std) ----
    float a[8];
    float A = 0.0f;
    double S1 = 0.0, S2 = 0.0;
#pragma unroll
    for (int i = 0; i < 8; ++i) {
      a[i] = ((m >> i) & 1u) ? 0.0f : fabsf(cur[i]);
      A = fmaxf(A, a[i]);
      S1 += (double)a[i];
      S2 += (double)a[i] * (double)a[i];
    }
#pragma unroll
    for (int o = 32; o > 0; o >>= 1) {
      A = fmaxf(A, __shfl_down(A, o, 64));
      S1 += __shfl_down(S1, o, 64);
      S2 += __shfl_down(S2, o, 64);
    }
    if (lane == 0) { redM[wid] = A; redS[wid][0] = S1; redS[wid][1] = S2; }
    __syncthreads();
    A = fmaxf(fmaxf(redM[0], redM[1]), fmaxf(redM[2], redM[3]));
    S1 = redS[0][0] + redS[1][0] + redS[2][0] + redS[3][0];
    S2 = redS[0][1] + redS[1][1] + redS[2][1] + redS[3][1];

    const float sv = valid ? s[tok] : 1.0f;
    if (tid == 0) {
      if (A / 7.0f > sv) atomicOr(&flagset[r * 32], 1u);  // record exact contribution
    }

    // ---- mask update under flag=1 assumption: a > mean + 3*std(ddof=1) ----
    const double n = (double)D_DIM;
    const double mean = S1 / n;
    double var = (S2 - n * mean * mean) / (n - 1.0);
    var = var > 0.0 ? var : 0.0;
    const double thr = mean + 3.0 * sqrt(var);
#pragma unroll
    for (int i = 0; i < 8; ++i)
      if ((double)a[i] > thr) m |= (1u << i);

    // ---- round 2: outlier dynamic scale (new mask) ----
    float O = 0.0f;
#pragma unroll
    for (int i = 0; i < 8; ++i)
      if ((m >> i) & 1u) O = fmaxf(O, fabsf(cur[i]));
#pragma unroll
    for (int o = 32; o > 0; o >>= 1) O = fmaxf(O, __shfl_down(O, o, 64));
    if (lane == 0) redO[wid] = O;
    __syncthreads();
    O = fmaxf(fmaxf(redO[0], redO[1]), fmaxf(redO[2], redO[3]));
    const float os = fmaxf(O, 1e-8f) / 127.0f;

    // ---- quantize + store ----
    if (valid) {
      float out[8];
#pragma unroll
      for (int i = 0; i < 8; ++i) {
        const bool mm = (m >> i) & 1u;
        const float inl = mm ? 0.0f : cur[i];
        const float orr = mm ? cur[i] : 0.0f;
        const float qi = fminf(fmaxf(rintf(inl / sv), -7.0f), 7.0f);
        const float qo = fminf(fmaxf(rintf(orr / os), -127.0f), 127.0f);
        out[i] = qi * sv + qo * os;
      }
      store8(y + base + (size_t)r * D_DIM, out);
    }

#pragma unroll
    for (int i = 0; i < 8; ++i) cur[i] = nxt[i];
  }
}

// ---------------- fallback: exact sequential, runs only if speculation failed ----------------
__device__ __forceinline__ void grid_barrier(uint* cnt, uint* gen) {
  __syncthreads();
  if (threadIdx.x == 0) {
    const uint my = __hip_atomic_load(gen, __ATOMIC_ACQUIRE, __HIP_MEMORY_SCOPE_AGENT);
    const uint old = __hip_atomic_fetch_add(cnt, 1u, __ATOMIC_ACQ_REL, __HIP_MEMORY_SCOPE_AGENT);
    if (old == FB_NBLK - 1) {
      __hip_atomic_store(cnt, 0u, __ATOMIC_RELAXED, __HIP_MEMORY_SCOPE_AGENT);
      __hip_atomic_store(gen, my + 1u, __ATOMIC_RELEASE, __HIP_MEMORY_SCOPE_AGENT);
    } else {
      while (__hip_atomic_load(gen, __ATOMIC_ACQUIRE, __HIP_MEMORY_SCOPE_AGENT) == my)
        __builtin_amdgcn_s_sleep(8);
    }
  }
  __syncthreads();
}

__global__ __launch_bounds__(256, 2) void qact_fallback(
    const float* __restrict__ x, const float* __restrict__ s, float* __restrict__ y,
    const uint* __restrict__ flagset, uint* __restrict__ flags2, uint* __restrict__ bar) {
  // If every speculative flag came out 1, speculation was exact (induction) -> done.
  bool ok = true;
#pragma unroll
  for (int r = 0; r < R_STEPS; ++r) ok &= (flagset[r * 32] != 0u);
  if (ok) return;

  __shared__ float redM[4];
  __shared__ double redS[4][2];
  __shared__ float redO[4];

  const int tid = threadIdx.x, lane = tid & 63, wid = tid >> 6;
  u64 mask = 0;  // 7 rows x 8 bits

  for (int r = 0; r < R_STEPS; ++r) {
    // ---- phase A: exact flag contributions with current masks ----
    for (int j = 0; j < 7; ++j) {
      const int row = blockIdx.x + FB_NBLK * j;
      if (row >= NROWS) break;  // block-uniform
      const int b = row / G_TOK, g = row % G_TOK;
      const int tok = g * R_STEPS + r;
      float A = 0.0f;
      if (tok < L_TOK) {
        const size_t off = ((size_t)b * L_TOK + tok) * D_DIM + (size_t)tid * 8;
        float v[8];
        load8(v, x + off);
        const uint mj = (uint)(mask >> (j * 8)) & 0xffu;
#pragma unroll
        for (int i = 0; i < 8; ++i)
          if (!((mj >> i) & 1u)) A = fmaxf(A, fabsf(v[i]));
      }
#pragma unroll
      for (int o = 32; o > 0; o >>= 1) A = fmaxf(A, __shfl_down(A, o, 64));
      if (lane == 0) redM[wid] = A;
      __syncthreads();
      A = fmaxf(fmaxf(redM[0], redM[1]), fmaxf(redM[2], redM[3]));
      const float sv = (tok < L_TOK) ? s[tok] : 1.0f;
      if (tid == 0 && A / 7.0f > sv) atomicOr(&flags2[r * 32], 1u);
      __syncthreads();
    }

    grid_barrier(&bar[0], &bar[1]);

    const uint f = __hip_atomic_load(&flags2[r * 32], __ATOMIC_ACQUIRE, __HIP_MEMORY_SCOPE_AGENT);

    // ---- phase B: mask update (if f), quantize, store ----
    for (int j = 0; j < 7; ++j) {
      const int row = blockIdx.x + FB_NBLK * j;
      if (row >= NROWS) break;
      const int b = row / G_TOK, g = row % G_TOK;
      const int tok = g * R_STEPS + r;
      const bool valid = tok < L_TOK;
      const size_t off = ((size_t)b * L_TOK + (valid ? tok : 0)) * D_DIM + (size_t)tid * 8;
      float v[8];
      if (valid) load8(v, x + off);
      else zero8(v);
      uint mj = (uint)(mask >> (j * 8)) & 0xffu;
      float a[8];
#pragma unroll
      for (int i = 0; i < 8; ++i) a[i] = ((mj >> i) & 1u) ? 0.0f : fabsf(v[i]);
      if (f) {  // grid-uniform
        double S1 = 0.0, S2 = 0.0;
#pragma unroll
        for (int i = 0; i < 8; ++i) {
          S1 += (double)a[i];
          S2 += (double)a[i] * (double)a[i];
        }
#pragma unroll
        for (int o = 32; o > 0; o >>= 1) {
          S1 += __shfl_down(S1, o, 64);
          S2 += __shfl_down(S2, o, 64);
        }
        if (lane == 0) { redS[wid][0] = S1; redS[wid][1] = S2; }
        __syncthreads();
        S1 = redS[0][0] + redS[1][0] + redS[2][0] + redS[3][0];
        S2 = redS[0][1] + redS[1][1] + redS[2][1] + redS[3][1];
        const double n = (double)D_DIM;
        const double mean = S1 / n;
        double var = (S2 - n * mean * mean) / (n - 1.0);
        var = var > 0.0 ? var : 0.0;
        const double thr = mean + 3.0 * sqrt(var);
#pragma unroll
        for (int i = 0; i < 8; ++i)
          if ((double)a[i] > thr) mj |= (1u << i);
        mask = (mask & ~((u64)0xffu << (j * 8))) | ((u64)mj << (j * 8));
        __syncthreads();
      }
      if (valid) {
        float O = 0.0f;
#pragma unroll
        for (int i = 0; i < 8; ++i)
          if ((mj >> i) & 1u) O = fmaxf(O, fabsf(v[i]));
#pragma unroll
        for (int o = 32; o > 0; o >>= 1) O = fmaxf(O, __shfl_down(O, o, 64));
        if (lane == 0) redO[wid] = O;
        __syncthreads();
        O = fmaxf(fmaxf(redO[0], redO[1]), fmaxf(redO[2], redO[3]));
        const float os = fmaxf(O, 1e-8f) / 127.0f;
        const float sv = s[tok];
        float out[8];
#pragma unroll
        for (int i = 0; i < 8; ++i) {
          const bool mm = (mj >> i) & 1u;
          const float inl = mm ? 0.0f : v[i];
          const float orr = mm ? v[i] : 0.0f;
          const float qi = fminf(fmaxf(rintf(inl / sv), -7.0f), 7.0f);
          const float qo = fminf(fmaxf(rintf(orr / os), -127.0f), 127.0f);
          out[i] = qi * sv + qo * os;
        }
        store8(y + off, out);
        __syncthreads();
      }
    }
  }
}

extern "C" void kernel_launch(void* const* d_in, const int* in_sizes, int n_in,
                              void* d_out, int out_size, void* d_ws, size_t ws_size,
                              hipStream_t stream) {
  const float* x = (const float*)d_in[0];
  const float* s = (const float*)d_in[1];
  float* y = (float*)d_out;
  uint* flagset = (uint*)d_ws;
  uint* flags2 = (uint*)((char*)d_ws + 2048);
  uint* bar = (uint*)((char*)d_ws + 3968);

  hipMemsetAsync(d_ws, 0, 4096, stream);
  qact_spec<<<NROWS, 256, 0, stream>>>(x, s, y, flagset);
  qact_fallback<<<FB_NBLK, 256, 0, stream>>>(x, s, y, flagset, flags2, bar);
}